// Round 2
// baseline (1537.178 us; speedup 1.0000x reference)
//
#include <hip/hip_runtime.h>
#include <hip/hip_bf16.h>
#include <stdint.h>

// ---------------- types ----------------
typedef __attribute__((ext_vector_type(4))) float f32x4;
typedef __attribute__((ext_vector_type(4))) unsigned int u32x4;
typedef __bf16 v8bf __attribute__((ext_vector_type(8)));

// async global->LDS, 16B per lane. LDS dest must be uniform + lane*16.
#define GLL16(gp, lp) __builtin_amdgcn_global_load_lds( \
    (const __attribute__((address_space(1))) unsigned int*)(const void*)(gp), \
    (__attribute__((address_space(3))) unsigned int*)(void*)(lp), 16, 0, 0)

// pack two f32 -> two bf16 (truncate) in one v_perm
__device__ __forceinline__ unsigned pkbf(float a, float b) {
  return __builtin_amdgcn_perm(__float_as_uint(b), __float_as_uint(a), 0x07060302u);
}

// ---------------- problem constants ----------------
// conv: [4,256,16,14,14] -> [4,512,16,14,14], 3x3x3 pad 1
// heads: K2 = 512*16 = 8192, M2 = 540+17280+36+72 = 17928, N2 = 4*196 = 784
#define OB1 423360      // out offset of bbox   (4*540*196)
#define OB2 13970880    // out offset of cls16  (OB1 + 4*17280*196)
#define OB3 13999104    // out offset of bbox16 (OB2 + 4*36*196)

// ws layout (bytes)
#define WS_XPAD   0
#define XPAD_GUARD_ELEMS 8192           /* 32 spatial slots * 256 ci */
#define WS_W1P    9519104               /* (32+18560)*256*2 */
#define WS_X2T    16596992              /* + 512*6912*2 */
#define WS_CLSS   31277056              /* + 896*8192*2 */
#define WS_CLS16S 32970496              /* + 540*784*4 */
#define WS_BIAS2  33083392              /* + 36*784*4 */

// ---------------- small prep kernels ----------------
__global__ void k_zero(u32x4* __restrict__ p) {
  p[blockIdx.x * 256 + threadIdx.x] = (u32x4){0u, 0u, 0u, 0u};   // 2324*256 = XPAD/16B exactly
}

// base_feat [b][ci][t][y][x] (fp32) -> Xpad_T bf16 [guard + b*4608 + (t+1)*256 + (y+1)*16 + (x+1)][ci]
__global__ void k_fill_xpad(const float* __restrict__ bf, __hip_bfloat16* __restrict__ xp) {
  __shared__ float tile[64][65];
  int spb = blockIdx.x, cib = blockIdx.y, b = blockIdx.z;
  int t = threadIdx.x;
  int c0 = t >> 6;           // 0..3
  int sp_l = t & 63;
  const float* src = bf + (size_t)(b * 256 + cib * 64) * 3136 + spb * 64;
#pragma unroll
  for (int i = 0; i < 16; ++i) {
    int ci_l = i * 4 + c0;
    tile[ci_l][sp_l] = src[ci_l * 3136 + sp_l];   // tile[channel][spatial]
  }
  __syncthreads();
  int ci_l = t & 63;
#pragma unroll
  for (int i = 0; i < 16; ++i) {
    int spl = i * 4 + c0;
    int sp = spb * 64 + spl;
    int tt = sp / 196; int rr = sp - tt * 196;
    int y = rr / 14;   int x = rr - y * 14;
    int s = b * 4608 + (tt + 1) * 256 + (y + 1) * 16 + (x + 1);
    // FIX(R1): was tile[spl][ci_l] — transposed channel/spatial within each 64x64 block.
    xp[(size_t)(32 + s) * 256 + cib * 64 + ci_l] = __float2bfloat16(tile[ci_l][spl]);
  }
}

// conv_w [co][ci][d] -> W1p bf16 [co][d*256+ci]
__global__ void k_pack_w1(const float* __restrict__ cw, __hip_bfloat16* __restrict__ w1p) {
  int i = blockIdx.x * 256 + threadIdx.x;      // 512*6912 exactly
  int co = i / 6912; int rem = i - co * 6912;
  int d = rem >> 8;  int ci = rem & 255;
  w1p[i] = __float2bfloat16(cw[co * 6912 + ci * 27 + d]);
}

__global__ void k_pack_bias2(const float* __restrict__ cb, const float* __restrict__ bb,
                             const float* __restrict__ c16, const float* __restrict__ b16,
                             float* __restrict__ bias2) {
  int i = blockIdx.x * 256 + threadIdx.x;
  if (i >= 18048) return;
  float v = 0.f;
  if (i < 540) v = cb[i];
  else if (i < 17820) v = bb[i - 540];
  else if (i < 17856) v = c16[i - 17820];
  else if (i < 17928) v = b16[i - 17856];
  bias2[i] = v;
}

// ---------------- GEMM1: conv as implicit GEMM ----------------
// A = W1p [512][6912] bf16, B = shifted Xpad_T, C -> relu(+bias) -> X2T[n2][co*16+t] bf16
// grid (128 ntile, 4 mtile), 256 thr. Columns: col = b*4096 + t*256 + y'*16 + x' (padded planes)
__global__ __launch_bounds__(256, 2) void k_gemm1(
    const __hip_bfloat16* __restrict__ W1p,
    const __hip_bfloat16* __restrict__ Xp,     // xpad + guard
    const float* __restrict__ conv_b,
    __hip_bfloat16* __restrict__ X2T) {
  __shared__ short lA[128 * 64];
  __shared__ short lB[128 * 64];
  const int tid = threadIdx.x;
  const int ntile = blockIdx.x, mtile = blockIdx.y;
  const int lane = tid & 63, wave = tid >> 6;
  const int wm = wave & 1, wn = wave >> 1;

  long gA[4]; long gB[4];
#pragma unroll
  for (int i = 0; i < 4; ++i) {
    int c = i * 256 + tid;
    int row = c >> 3, pos = c & 7;
    int kc = pos ^ (row & 7);                  // global chunk for swizzled slot
    gA[i] = (long)(mtile * 128 + row) * 6912 + kc * 8;
    int col = ntile * 128 + row;
    int bi = col >> 12, rem = col & 4095;
    gB[i] = (long)(bi * 4608 + rem) * 256 + kc * 8;
  }
  f32x4 acc[4][4] = {};

  for (int d = 0; d < 27; ++d) {
    int dt = d / 9; int r9 = d - dt * 9; int dy = r9 / 3; int dx = r9 - dy * 3;
    long offd = (long)(dt * 256 + (dy - 1) * 16 + (dx - 1)) * 256;
    int kd = d * 256;
    for (int ci0 = 0; ci0 < 256; ci0 += 64) {
#pragma unroll
      for (int i = 0; i < 4; ++i) {
        GLL16(W1p + gA[i] + (kd + ci0), &lA[(i * 256 + tid) * 8]);
        GLL16(Xp + gB[i] + offd + ci0, &lB[(i * 256 + tid) * 8]);
      }
      __syncthreads();
#pragma unroll
      for (int ks = 0; ks < 2; ++ks) {
        v8bf af[4], bfr[4];
#pragma unroll
        for (int mi = 0; mi < 4; ++mi) {
          int row = wm * 64 + mi * 16 + (lane & 15);
          int ch = (ks * 4 + (lane >> 4)) ^ (row & 7);
          af[mi] = *(const v8bf*)&lA[row * 64 + ch * 8];
        }
#pragma unroll
        for (int ni = 0; ni < 4; ++ni) {
          int row = wn * 64 + ni * 16 + (lane & 15);
          int ch = (ks * 4 + (lane >> 4)) ^ (row & 7);
          bfr[ni] = *(const v8bf*)&lB[row * 64 + ch * 8];
        }
#pragma unroll
        for (int mi = 0; mi < 4; ++mi)
#pragma unroll
          for (int ni = 0; ni < 4; ++ni)
            acc[mi][ni] = __builtin_amdgcn_mfma_f32_16x16x32_bf16(af[mi], bfr[ni], acc[mi][ni], 0, 0, 0);
      }
      __syncthreads();
    }
  }
  // epilogue: bias + relu, write bf16 to X2T[n2][co*16+t]
#pragma unroll
  for (int ni = 0; ni < 4; ++ni) {
    int col = ntile * 128 + wn * 64 + ni * 16 + (lane & 15);
    int bi = col >> 12, rem = col & 4095;
    int tt = rem >> 8, p2 = rem & 255;
    int yq = p2 >> 4, xq = p2 & 15;
    if (yq < 1 || yq > 14 || xq < 1 || xq > 14) continue;
    int n2 = bi * 196 + (yq - 1) * 14 + (xq - 1);
#pragma unroll
    for (int mi = 0; mi < 4; ++mi) {
#pragma unroll
      for (int rg = 0; rg < 4; ++rg) {
        int co = mtile * 128 + wm * 64 + mi * 16 + (lane >> 4) * 4 + rg;
        float v = acc[mi][ni][rg] + conv_b[co];
        v = fmaxf(v, 0.f);
        X2T[(size_t)n2 * 8192 + co * 16 + tt] = __float2bfloat16(v);
      }
    }
  }
}

// ---------------- GEMM2: heads ----------------
// A = fp32 head weights (converted in-register), B = X2T bf16 [n][k]. grid (7 ntile, 141 mtile)
__global__ __launch_bounds__(256, 2) void k_gemm2(
    const float* __restrict__ cls_w, const float* __restrict__ bbox_w,
    const float* __restrict__ cls16_w, const float* __restrict__ bbox16_w,
    const __hip_bfloat16* __restrict__ X2T, const float* __restrict__ bias2,
    float* __restrict__ out, float* __restrict__ cls_s, float* __restrict__ cls16_s) {
  __shared__ short lA[128 * 64];
  __shared__ short lB[128 * 64];
  const int tid = threadIdx.x;
  const int ntile = blockIdx.x, mtile = blockIdx.y;
  const int lane = tid & 63, wave = tid >> 6;
  const int wm = wave & 1, wn = wave >> 1;

  const int r = tid >> 1, h = tid & 1;          // A staging: row r, half h (32 floats each)
  const float* rowptr;
  {
    int o = mtile * 128 + r;
    if (o >= 17928) o = 0;                      // pad rows -> finite dummy
    if (o < 540) rowptr = cls_w + (size_t)o * 8192;
    else if (o < 17820) rowptr = bbox_w + (size_t)(o - 540) * 8192;
    else if (o < 17856) rowptr = cls16_w + (size_t)(o - 17820) * 8192;
    else rowptr = bbox16_w + (size_t)(o - 17856) * 8192;
    rowptr += h * 32;
  }
  long gB[4];
#pragma unroll
  for (int i = 0; i < 4; ++i) {
    int c = i * 256 + tid;
    int row = c >> 3, pos = c & 7;
    int kc = pos ^ (row & 7);
    gB[i] = (long)(ntile * 128 + row) * 8192 + kc * 8;
  }
  f32x4 acc[4][4] = {};

  for (int k0 = 0; k0 < 8192; k0 += 64) {
#pragma unroll
    for (int i = 0; i < 4; ++i)
      GLL16(X2T + gB[i] + k0, &lB[(i * 256 + tid) * 8]);
    const float4* p = (const float4*)(rowptr + k0);
    float4 v[8];
#pragma unroll
    for (int j = 0; j < 8; ++j) v[j] = p[j];
#pragma unroll
    for (int j = 0; j < 4; ++j) {
      u32x4 w;
      w.x = pkbf(v[2 * j].x, v[2 * j].y);
      w.y = pkbf(v[2 * j].z, v[2 * j].w);
      w.z = pkbf(v[2 * j + 1].x, v[2 * j + 1].y);
      w.w = pkbf(v[2 * j + 1].z, v[2 * j + 1].w);
      int pos = (h * 4 + j) ^ (r & 7);
      *(u32x4*)&lA[r * 64 + pos * 8] = w;
    }
    __syncthreads();
#pragma unroll
    for (int ks = 0; ks < 2; ++ks) {
      v8bf af[4], bfr[4];
#pragma unroll
      for (int mi = 0; mi < 4; ++mi) {
        int row = wm * 64 + mi * 16 + (lane & 15);
        int ch = (ks * 4 + (lane >> 4)) ^ (row & 7);
        af[mi] = *(const v8bf*)&lA[row * 64 + ch * 8];
      }
#pragma unroll
      for (int ni = 0; ni < 4; ++ni) {
        int row = wn * 64 + ni * 16 + (lane & 15);
        int ch = (ks * 4 + (lane >> 4)) ^ (row & 7);
        bfr[ni] = *(const v8bf*)&lB[row * 64 + ch * 8];
      }
#pragma unroll
      for (int mi = 0; mi < 4; ++mi)
#pragma unroll
        for (int ni = 0; ni < 4; ++ni)
          acc[mi][ni] = __builtin_amdgcn_mfma_f32_16x16x32_bf16(af[mi], bfr[ni], acc[mi][ni], 0, 0, 0);
    }
    __syncthreads();
  }
  // epilogue: + bias, route to out / score buffers
#pragma unroll
  for (int ni = 0; ni < 4; ++ni) {
    int col = ntile * 128 + wn * 64 + ni * 16 + (lane & 15);
    if (col >= 784) continue;
    int bi = col / 196, yx = col - bi * 196;
#pragma unroll
    for (int mi = 0; mi < 4; ++mi) {
#pragma unroll
      for (int rg = 0; rg < 4; ++rg) {
        int o = mtile * 128 + wm * 64 + mi * 16 + (lane >> 4) * 4 + rg;
        if (o >= 17928) continue;
        float val = acc[mi][ni][rg] + bias2[o];
        if (o < 540) cls_s[o * 784 + col] = val;
        else if (o < 17820) out[OB1 + ((size_t)bi * 17280 + (o - 540)) * 196 + yx] = val;
        else if (o < 17856) cls16_s[(o - 17820) * 784 + col] = val;
        else out[OB3 + ((size_t)bi * 72 + (o - 17856)) * 196 + yx] = val;
      }
    }
  }
}

// ---------------- pair softmax ----------------
__global__ void k_softmax_pairs(const float* __restrict__ s, float* __restrict__ out,
                                int half, int nc, long obase) {
  int idx = blockIdx.x * 256 + threadIdx.x;
  if (idx >= half * 784) return;
  int i = idx / 784, col = idx - i * 784;
  float s0 = s[i * 784 + col];
  float s1 = s[(i + half) * 784 + col];
  float m = fmaxf(s0, s1);
  float e0 = __expf(s0 - m), e1 = __expf(s1 - m);
  float inv = 1.0f / (e0 + e1);
  int bi = col / 196, yx = col - bi * 196;
  out[obase + ((size_t)bi * nc + i) * 196 + yx] = e0 * inv;
  out[obase + ((size_t)bi * nc + i + half) * 196 + yx] = e1 * inv;
}

// ---------------- launch ----------------
extern "C" void kernel_launch(void* const* d_in, const int* in_sizes, int n_in,
                              void* d_out, int out_size, void* d_ws, size_t ws_size,
                              hipStream_t stream) {
  const float* base_feat = (const float*)d_in[0];
  const float* conv_w = (const float*)d_in[4];
  const float* conv_b = (const float*)d_in[5];
  const float* cls_w = (const float*)d_in[6];
  const float* cls_b = (const float*)d_in[7];
  const float* bbox_w = (const float*)d_in[8];
  const float* bbox_b = (const float*)d_in[9];
  const float* cls16_w = (const float*)d_in[10];
  const float* cls16_b = (const float*)d_in[11];
  const float* bbox16_w = (const float*)d_in[12];
  const float* bbox16_b = (const float*)d_in[13];
  float* out = (float*)d_out;
  char* ws = (char*)d_ws;

  __hip_bfloat16* xpad = (__hip_bfloat16*)(ws + WS_XPAD);
  __hip_bfloat16* w1p = (__hip_bfloat16*)(ws + WS_W1P);
  __hip_bfloat16* x2t = (__hip_bfloat16*)(ws + WS_X2T);
  float* cls_s = (float*)(ws + WS_CLSS);
  float* cls16_s = (float*)(ws + WS_CLS16S);
  float* bias2 = (float*)(ws + WS_BIAS2);

  dim3 blk(256);
  k_zero<<<dim3(2324), blk, 0, stream>>>((u32x4*)(ws + WS_XPAD));
  k_fill_xpad<<<dim3(49, 4, 4), blk, 0, stream>>>(base_feat, xpad);
  k_pack_w1<<<dim3(13824), blk, 0, stream>>>(conv_w, w1p);
  k_pack_bias2<<<dim3(71), blk, 0, stream>>>(cls_b, bbox_b, cls16_b, bbox16_b, bias2);
  k_gemm1<<<dim3(128, 4), blk, 0, stream>>>(w1p, xpad + XPAD_GUARD_ELEMS, conv_b, x2t);
  k_gemm2<<<dim3(7, 141), blk, 0, stream>>>(cls_w, bbox_w, cls16_w, bbox16_w, x2t, bias2,
                                            out, cls_s, cls16_s);
  k_softmax_pairs<<<dim3(827), blk, 0, stream>>>(cls_s, out, 270, 540, 0L);
  k_softmax_pairs<<<dim3(56), blk, 0, stream>>>(cls16_s, out, 18, 36, (long)OB2);
}

// Round 3
// 1495.679 us; speedup vs baseline: 1.0277x; 1.0277x over previous
//
#include <hip/hip_runtime.h>
#include <hip/hip_bf16.h>
#include <stdint.h>

// ---------------- types ----------------
typedef __attribute__((ext_vector_type(4))) float f32x4;
typedef __attribute__((ext_vector_type(4))) unsigned int u32x4;
typedef __bf16 v8bf __attribute__((ext_vector_type(8)));

// async global->LDS, 16B per lane. LDS dest must be uniform + lane*16.
#define GLL16(gp, lp) __builtin_amdgcn_global_load_lds( \
    (const __attribute__((address_space(1))) unsigned int*)(const void*)(gp), \
    (__attribute__((address_space(3))) unsigned int*)(void*)(lp), 16, 0, 0)

// pack two f32 -> two bf16 (truncate): short0=bf16(a) (lower k), short1=bf16(b)
__device__ __forceinline__ unsigned pkbf(float a, float b) {
  return __builtin_amdgcn_perm(__float_as_uint(b), __float_as_uint(a), 0x07060302u);
}

// ---------------- problem constants ----------------
// conv: [4,256,16,14,14] -> [4,512,16,14,14], 3x3x3 pad 1
// heads: K2 = 512*16 = 8192, M2 = 540+17280+36+72 = 17928, N2 = 4*196 = 784
#define OB1 423360      // out offset of bbox   (4*540*196)
#define OB2 13970880    // out offset of cls16  (OB1 + 4*17280*196)
#define OB3 13999104    // out offset of bbox16 (OB2 + 4*36*196)

// ws layout (bytes)
#define WS_XPAD   0
#define XPAD_GUARD_ELEMS 8192           /* 32 spatial slots * 256 ci */
#define WS_W1P    9519104               /* (32+18560)*256*2 */
#define WS_X2T    16596992              /* + 512*6912*2 */
#define WS_CLSS   31277056              /* + 896*8192*2 (X2T uses 832 rows of 896) */
#define WS_CLS16S 32970496              /* + 540*784*4 */
#define WS_BIAS2  33083392              /* + 36*784*4 */

// ---------------- small prep kernels ----------------
__global__ void k_zero(u32x4* __restrict__ p) {
  p[blockIdx.x * 256 + threadIdx.x] = (u32x4){0u, 0u, 0u, 0u};   // 2324*256 = XPAD/16B exactly
}

// base_feat [b][ci][t][y][x] (fp32) -> Xpad_T bf16 [guard + b*4608 + (t+1)*256 + (y+1)*16 + (x+1)][ci]
__global__ void k_fill_xpad(const float* __restrict__ bf, __hip_bfloat16* __restrict__ xp) {
  __shared__ float tile[64][65];
  int spb = blockIdx.x, cib = blockIdx.y, b = blockIdx.z;
  int t = threadIdx.x;
  int c0 = t >> 6;           // 0..3
  int sp_l = t & 63;
  const float* src = bf + (size_t)(b * 256 + cib * 64) * 3136 + spb * 64;
#pragma unroll
  for (int i = 0; i < 16; ++i) {
    int ci_l = i * 4 + c0;
    tile[ci_l][sp_l] = src[ci_l * 3136 + sp_l];   // tile[channel][spatial]
  }
  __syncthreads();
  int ci_l = t & 63;
#pragma unroll
  for (int i = 0; i < 16; ++i) {
    int spl = i * 4 + c0;
    int sp = spb * 64 + spl;
    int tt = sp / 196; int rr = sp - tt * 196;
    int y = rr / 14;   int x = rr - y * 14;
    int s = b * 4608 + (tt + 1) * 256 + (y + 1) * 16 + (x + 1);
    xp[(size_t)(32 + s) * 256 + cib * 64 + ci_l] = __float2bfloat16(tile[ci_l][spl]);
  }
}

// conv_w [co][ci][d] -> W1p bf16 [co][d*256+ci]
__global__ void k_pack_w1(const float* __restrict__ cw, __hip_bfloat16* __restrict__ w1p) {
  int i = blockIdx.x * 256 + threadIdx.x;      // 512*6912 exactly
  int co = i / 6912; int rem = i - co * 6912;
  int d = rem >> 8;  int ci = rem & 255;
  w1p[i] = __float2bfloat16(cw[co * 6912 + ci * 27 + d]);
}

__global__ void k_pack_bias2(const float* __restrict__ cb, const float* __restrict__ bb,
                             const float* __restrict__ c16, const float* __restrict__ b16,
                             float* __restrict__ bias2) {
  int i = blockIdx.x * 256 + threadIdx.x;
  if (i >= 18048) return;
  float v = 0.f;
  if (i < 540) v = cb[i];
  else if (i < 17820) v = bb[i - 540];
  else if (i < 17856) v = c16[i - 17820];
  else if (i < 17928) v = b16[i - 17856];
  bias2[i] = v;
}

// ---------------- GEMM1: conv as implicit GEMM ----------------
// A = W1p [512][6912] bf16, B = shifted Xpad_T, C -> relu(+bias) -> X2T[n2p][co*16+t] bf16
// R3: BM=64 x BN=128, grid (128 ntile, 8 mtile) = 1024 blocks = 4/CU (was 512 = 2/CU).
__global__ __launch_bounds__(256, 4) void k_gemm1(
    const __hip_bfloat16* __restrict__ W1p,
    const __hip_bfloat16* __restrict__ Xp,     // xpad + guard
    const float* __restrict__ conv_b,
    __hip_bfloat16* __restrict__ X2T) {
  __shared__ short lA[64 * 64];
  __shared__ short lB[128 * 64];
  const int tid = threadIdx.x;
  const int ntile = blockIdx.x, mtile = blockIdx.y;
  const int lane = tid & 63, wave = tid >> 6;
  const int wm = wave & 1, wn = wave >> 1;

  long gA[2]; long gB[4];
#pragma unroll
  for (int i = 0; i < 2; ++i) {
    int c = i * 256 + tid;
    int row = c >> 3, pos = c & 7;
    int kc = pos ^ (row & 7);
    gA[i] = (long)(mtile * 64 + row) * 6912 + kc * 8;
  }
#pragma unroll
  for (int i = 0; i < 4; ++i) {
    int c = i * 256 + tid;
    int row = c >> 3, pos = c & 7;
    int kc = pos ^ (row & 7);
    int col = ntile * 128 + row;
    int bi = col >> 12, rem = col & 4095;
    gB[i] = (long)(bi * 4608 + rem) * 256 + kc * 8;
  }
  f32x4 acc[2][4] = {};

  for (int d = 0; d < 27; ++d) {
    int dt = d / 9; int r9 = d - dt * 9; int dy = r9 / 3; int dx = r9 - dy * 3;
    long offd = (long)(dt * 256 + (dy - 1) * 16 + (dx - 1)) * 256;
    int kd = d * 256;
    for (int ci0 = 0; ci0 < 256; ci0 += 64) {
#pragma unroll
      for (int i = 0; i < 2; ++i)
        GLL16(W1p + gA[i] + (kd + ci0), &lA[(i * 256 + tid) * 8]);
#pragma unroll
      for (int i = 0; i < 4; ++i)
        GLL16(Xp + gB[i] + offd + ci0, &lB[(i * 256 + tid) * 8]);
      __syncthreads();
#pragma unroll
      for (int ks = 0; ks < 2; ++ks) {
        v8bf af[2], bfr[4];
#pragma unroll
        for (int mi = 0; mi < 2; ++mi) {
          int row = wm * 32 + mi * 16 + (lane & 15);
          int ch = (ks * 4 + (lane >> 4)) ^ (row & 7);
          af[mi] = *(const v8bf*)&lA[row * 64 + ch * 8];
        }
#pragma unroll
        for (int ni = 0; ni < 4; ++ni) {
          int row = wn * 64 + ni * 16 + (lane & 15);
          int ch = (ks * 4 + (lane >> 4)) ^ (row & 7);
          bfr[ni] = *(const v8bf*)&lB[row * 64 + ch * 8];
        }
#pragma unroll
        for (int mi = 0; mi < 2; ++mi)
#pragma unroll
          for (int ni = 0; ni < 4; ++ni)
            acc[mi][ni] = __builtin_amdgcn_mfma_f32_16x16x32_bf16(af[mi], bfr[ni], acc[mi][ni], 0, 0, 0);
      }
      __syncthreads();
    }
  }
  // epilogue: bias + relu, write bf16 to X2T[n2p][co*16+t], n2p = b*208 + y*14 + x
#pragma unroll
  for (int ni = 0; ni < 4; ++ni) {
    int col = ntile * 128 + wn * 64 + ni * 16 + (lane & 15);
    int bi = col >> 12, rem = col & 4095;
    int tt = rem >> 8, p2 = rem & 255;
    int yq = p2 >> 4, xq = p2 & 15;
    if (yq < 1 || yq > 14 || xq < 1 || xq > 14) continue;
    int n2p = bi * 208 + (yq - 1) * 14 + (xq - 1);
#pragma unroll
    for (int mi = 0; mi < 2; ++mi) {
#pragma unroll
      for (int rg = 0; rg < 4; ++rg) {
        int co = mtile * 64 + wm * 32 + mi * 16 + (lane >> 4) * 4 + rg;
        float v = acc[mi][ni][rg] + conv_b[co];
        v = fmaxf(v, 0.f);
        X2T[(size_t)n2p * 8192 + co * 16 + tt] = __float2bfloat16(v);
      }
    }
  }
}

// ---------------- GEMM2: heads ----------------
// R3: BM=64, BN=416 (2 ntiles instead of 7 -> A fp32 read 2x not 7x).
// B = X2T bf16 [832][8192] (4 batches x 208-padded cols). grid (2 ntile, 281 mtile).
// Waves 2x2: each wave 32 rows x 208 cols (2 m-tiles x 13 n-tiles, acc=104 VGPR).
__global__ __launch_bounds__(256, 2) void k_gemm2(
    const float* __restrict__ cls_w, const float* __restrict__ bbox_w,
    const float* __restrict__ cls16_w, const float* __restrict__ bbox16_w,
    const __hip_bfloat16* __restrict__ X2T, const float* __restrict__ bias2,
    float* __restrict__ out, float* __restrict__ cls_s, float* __restrict__ cls16_s) {
  __shared__ short lA[64 * 64];      // 8 KB
  __shared__ short lB[416 * 64];     // 52 KB
  const int tid = threadIdx.x;
  const int ntile = blockIdx.x, mtile = blockIdx.y;
  const int lane = tid & 63, wave = tid >> 6;
  const int wm = wave & 1, wn = wave >> 1;

  // A staging: thread t handles row r = t>>2, quarter q = t&3 (16 floats each)
  const int r = tid >> 2, q = tid & 3;
  const float* rowptr;
  {
    int o = mtile * 64 + r;
    if (o >= 17928) o = 0;                      // pad rows -> finite dummy
    if (o < 540) rowptr = cls_w + (size_t)o * 8192;
    else if (o < 17820) rowptr = bbox_w + (size_t)(o - 540) * 8192;
    else if (o < 17856) rowptr = cls16_w + (size_t)(o - 17820) * 8192;
    else rowptr = bbox16_w + (size_t)(o - 17856) * 8192;
    rowptr += q * 16;
  }
  const int pos0 = (q * 2) ^ (r & 7), pos1 = (q * 2 + 1) ^ (r & 7);

  long gB[13];
#pragma unroll
  for (int i = 0; i < 13; ++i) {
    int c = i * 256 + tid;
    int row = c >> 3, pos = c & 7;
    int kc = pos ^ (row & 7);
    gB[i] = (long)(ntile * 416 + row) * 8192 + kc * 8;
  }
  f32x4 acc[2][13] = {};

  // prefetch A for k0 = 0
  float4 v0, v1, v2, v3;
  {
    const float4* p = (const float4*)rowptr;
    v0 = p[0]; v1 = p[1]; v2 = p[2]; v3 = p[3];
  }

  for (int k0 = 0; k0 < 8192; k0 += 64) {
#pragma unroll
    for (int i = 0; i < 13; ++i)
      GLL16(X2T + gB[i] + k0, &lB[(i * 256 + tid) * 8]);
    // stage prefetched A (fp32 -> bf16)
    {
      u32x4 w0, w1;
      w0.x = pkbf(v0.x, v0.y); w0.y = pkbf(v0.z, v0.w);
      w0.z = pkbf(v1.x, v1.y); w0.w = pkbf(v1.z, v1.w);
      w1.x = pkbf(v2.x, v2.y); w1.y = pkbf(v2.z, v2.w);
      w1.z = pkbf(v3.x, v3.y); w1.w = pkbf(v3.z, v3.w);
      *(u32x4*)&lA[r * 64 + pos0 * 8] = w0;
      *(u32x4*)&lA[r * 64 + pos1 * 8] = w1;
    }
    // prefetch A for next k-step (hidden under MFMA phase)
    if (k0 + 64 < 8192) {
      const float4* p = (const float4*)(rowptr + k0 + 64);
      v0 = p[0]; v1 = p[1]; v2 = p[2]; v3 = p[3];
    }
    __syncthreads();
#pragma unroll
    for (int ks = 0; ks < 2; ++ks) {
      v8bf af[2];
#pragma unroll
      for (int mi = 0; mi < 2; ++mi) {
        int row = wm * 32 + mi * 16 + (lane & 15);
        int ch = (ks * 4 + (lane >> 4)) ^ (row & 7);
        af[mi] = *(const v8bf*)&lA[row * 64 + ch * 8];
      }
#pragma unroll
      for (int ni = 0; ni < 13; ++ni) {
        int row = wn * 208 + ni * 16 + (lane & 15);
        int ch = (ks * 4 + (lane >> 4)) ^ (row & 7);
        v8bf bfr = *(const v8bf*)&lB[row * 64 + ch * 8];
        acc[0][ni] = __builtin_amdgcn_mfma_f32_16x16x32_bf16(af[0], bfr, acc[0][ni], 0, 0, 0);
        acc[1][ni] = __builtin_amdgcn_mfma_f32_16x16x32_bf16(af[1], bfr, acc[1][ni], 0, 0, 0);
      }
    }
    __syncthreads();
  }
  // epilogue: + bias, route to out / score buffers
  const int batch = ntile * 2 + wn;
#pragma unroll
  for (int ni = 0; ni < 13; ++ni) {
    int cib = ni * 16 + (lane & 15);            // col within batch, 0..207
    if (cib >= 196) continue;
    int col = batch * 196 + cib;                // 0..783 (cls_s/cls16_s column)
#pragma unroll
    for (int mi = 0; mi < 2; ++mi) {
#pragma unroll
      for (int rg = 0; rg < 4; ++rg) {
        int o = mtile * 64 + wm * 32 + mi * 16 + (lane >> 4) * 4 + rg;
        if (o >= 17928) continue;
        float val = acc[mi][ni][rg] + bias2[o];
        if (o < 540) cls_s[o * 784 + col] = val;
        else if (o < 17820) out[OB1 + ((size_t)batch * 17280 + (o - 540)) * 196 + cib] = val;
        else if (o < 17856) cls16_s[(o - 17820) * 784 + col] = val;
        else out[OB3 + ((size_t)batch * 72 + (o - 17856)) * 196 + cib] = val;
      }
    }
  }
}

// ---------------- pair softmax ----------------
__global__ void k_softmax_pairs(const float* __restrict__ s, float* __restrict__ out,
                                int half, int nc, long obase) {
  int idx = blockIdx.x * 256 + threadIdx.x;
  if (idx >= half * 784) return;
  int i = idx / 784, col = idx - i * 784;
  float s0 = s[i * 784 + col];
  float s1 = s[(i + half) * 784 + col];
  float m = fmaxf(s0, s1);
  float e0 = __expf(s0 - m), e1 = __expf(s1 - m);
  float inv = 1.0f / (e0 + e1);
  int bi = col / 196, yx = col - bi * 196;
  out[obase + ((size_t)bi * nc + i) * 196 + yx] = e0 * inv;
  out[obase + ((size_t)bi * nc + i + half) * 196 + yx] = e1 * inv;
}

// ---------------- launch ----------------
extern "C" void kernel_launch(void* const* d_in, const int* in_sizes, int n_in,
                              void* d_out, int out_size, void* d_ws, size_t ws_size,
                              hipStream_t stream) {
  const float* base_feat = (const float*)d_in[0];
  const float* conv_w = (const float*)d_in[4];
  const float* conv_b = (const float*)d_in[5];
  const float* cls_w = (const float*)d_in[6];
  const float* cls_b = (const float*)d_in[7];
  const float* bbox_w = (const float*)d_in[8];
  const float* bbox_b = (const float*)d_in[9];
  const float* cls16_w = (const float*)d_in[10];
  const float* cls16_b = (const float*)d_in[11];
  const float* bbox16_w = (const float*)d_in[12];
  const float* bbox16_b = (const float*)d_in[13];
  float* out = (float*)d_out;
  char* ws = (char*)d_ws;

  __hip_bfloat16* xpad = (__hip_bfloat16*)(ws + WS_XPAD);
  __hip_bfloat16* w1p = (__hip_bfloat16*)(ws + WS_W1P);
  __hip_bfloat16* x2t = (__hip_bfloat16*)(ws + WS_X2T);
  float* cls_s = (float*)(ws + WS_CLSS);
  float* cls16_s = (float*)(ws + WS_CLS16S);
  float* bias2 = (float*)(ws + WS_BIAS2);

  dim3 blk(256);
  k_zero<<<dim3(2324), blk, 0, stream>>>((u32x4*)(ws + WS_XPAD));
  k_fill_xpad<<<dim3(49, 4, 4), blk, 0, stream>>>(base_feat, xpad);
  k_pack_w1<<<dim3(13824), blk, 0, stream>>>(conv_w, w1p);
  k_pack_bias2<<<dim3(71), blk, 0, stream>>>(cls_b, bbox_b, cls16_b, bbox16_b, bias2);
  k_gemm1<<<dim3(128, 8), blk, 0, stream>>>(w1p, xpad + XPAD_GUARD_ELEMS, conv_b, x2t);
  k_gemm2<<<dim3(2, 281), blk, 0, stream>>>(cls_w, bbox_w, cls16_w, bbox16_w, x2t, bias2,
                                            out, cls_s, cls16_s);
  k_softmax_pairs<<<dim3(827), blk, 0, stream>>>(cls_s, out, 270, 540, 0L);
  k_softmax_pairs<<<dim3(56), blk, 0, stream>>>(cls16_s, out, 18, 36, (long)OB2);
}